// Round 4
// baseline (243.663 us; speedup 1.0000x reference)
//
#include <hip/hip_runtime.h>

#define BN_EPS 1e-3f

typedef float vf4 __attribute__((ext_vector_type(4)));     // native vector for builtins
typedef _Float16 half8 __attribute__((ext_vector_type(8))); // 16B of fp16

// ---- order-preserving float<->uint key for atomicMax on floats ----
__device__ __forceinline__ unsigned int f2k(float f) {
    unsigned int u = __float_as_uint(f);
    return (u & 0x80000000u) ? ~u : (u | 0x80000000u);
}
__device__ __forceinline__ float k2f(unsigned int u) {
    return __uint_as_float((u & 0x80000000u) ? (u & 0x7FFFFFFFu) : ~u);
}

// Kernel 1: per-node precompute.
//   y2h[n,s,h] = (fp16) sum_f x[n,f] * Wk[s, f*H + h]   for s<8
//   y2h[n,8,h] = (fp16) sum_f x[n,f] * bk[f*H + h]      (bias row, edge coeff 1.0)
//   agg[n,h]   = sum_f x[n,f] * Wr[f,h] + br[h]         (base folded into agg init)
// Also initializes pooled_u (block 0).
template <int S, int F, int H>
__global__ void node_pre(const float* __restrict__ x,
                         const float* __restrict__ Wk,
                         const float* __restrict__ bk,
                         const float* __restrict__ Wr,
                         const float* __restrict__ br,
                         _Float16* __restrict__ y2h,   // [N, S+1, H] fp16
                         float* __restrict__ agg,      // [N, H] fp32
                         unsigned int* __restrict__ pooled_u,
                         int N) {
    if (blockIdx.x == 0 && threadIdx.x < H) pooled_u[threadIdx.x] = 0u;

    int t = blockIdx.x * blockDim.x + threadIdx.x;
    int n = t / H;
    int h = t % H;
    if (n >= N) return;

    float xf[F];
#pragma unroll
    for (int f = 0; f < F; ++f) xf[f] = x[n * F + f];

    _Float16* yrow = y2h + (size_t)n * (S + 1) * H + h;
#pragma unroll
    for (int s = 0; s < S; ++s) {
        float acc = 0.f;
#pragma unroll
        for (int f = 0; f < F; ++f) acc += xf[f] * Wk[(s * F + f) * H + h];
        yrow[s * H] = (_Float16)acc;
    }

    float accb = 0.f, accr = 0.f;
#pragma unroll
    for (int f = 0; f < F; ++f) {
        accb += xf[f] * bk[f * H + h];
        accr += xf[f] * Wr[f * H + h];
    }
    yrow[S * H] = (_Float16)accb;             // bias row (coeff 1.0 per edge)
    agg[(size_t)n * H + h] = accr + br[h];    // base folded into agg init
}

// Kernel 2: per-edge message + scatter-add. 2 lanes per edge; each lane
// covers 8 of the 16 h-channels via 16B half8 gathers.
//   msg[h] = sum_{s<=8} es[s] * y2h[src, s, h];  agg[dst, h] += msg[h]
template <int S, int H>
__global__ void edge_scatter(const float* __restrict__ efeat,
                             const int* __restrict__ src,
                             const int* __restrict__ dst,
                             const _Float16* __restrict__ y2h,  // [N, S+1, H]
                             float* __restrict__ agg,
                             int E) {
    int t = blockIdx.x * blockDim.x + threadIdx.x;
    int edge = t >> 1;
    int hi = t & 1;       // which 8-wide half of the H=16 row
    if (edge >= E) return;

    int sn = __builtin_nontemporal_load(src + edge);
    int dn = __builtin_nontemporal_load(dst + edge);

    // streamed edge features: non-temporal, don't pollute caches (y2h lives there)
    const vf4* e4 = (const vf4*)(efeat + (size_t)edge * S);
    vf4 ea = __builtin_nontemporal_load(e4);
    vf4 eb = __builtin_nontemporal_load(e4 + 1);
    float es[S + 1] = {ea.x, ea.y, ea.z, ea.w, eb.x, eb.y, eb.z, eb.w, 1.0f};

    const _Float16* yb = y2h + (size_t)sn * (S + 1) * H + hi * 8;
    float m[8] = {0.f, 0.f, 0.f, 0.f, 0.f, 0.f, 0.f, 0.f};
#pragma unroll
    for (int s = 0; s <= S; ++s) {
        half8 hv = *(const half8*)(yb + s * H);
#pragma unroll
        for (int j = 0; j < 8; ++j) m[j] += es[s] * (float)hv[j];
    }

    float* ap = agg + (size_t)dn * H + hi * 8;
#pragma unroll
    for (int j = 0; j < 8; ++j) unsafeAtomicAdd(ap + j, m[j]);
}

// Kernel 3: h = BN(relu(agg)); global max per h.
template <int H>
__global__ void bn_relu_max(const float* __restrict__ agg,
                            const float* __restrict__ gamma,
                            const float* __restrict__ beta,
                            const float* __restrict__ mmean,
                            const float* __restrict__ mvar,
                            unsigned int* __restrict__ pooled_u,
                            int N) {
    __shared__ unsigned int smax[H];
    if (threadIdx.x < H) smax[threadIdx.x] = 0u;
    __syncthreads();

    int t = blockIdx.x * blockDim.x + threadIdx.x;
    int stride = gridDim.x * blockDim.x;  // multiple of H
    int h = t % H;

    float scale = gamma[h] * rsqrtf(mvar[h] + BN_EPS);
    float shift = beta[h] - mmean[h] * scale;

    float best = -INFINITY;
    int total = N * H;
    for (int i = t; i < total; i += stride) {
        float v = agg[i];
        v = v > 0.f ? v : 0.f;          // relu
        v = v * scale + shift;          // BN (inference)
        best = fmaxf(best, v);
    }
    atomicMax(&smax[h], f2k(best));
    __syncthreads();
    if (threadIdx.x < H) atomicMax(&pooled_u[threadIdx.x], smax[threadIdx.x]);
}

// Kernel 4: out[j] = bd[j] + sum_h pooled[h] * Wd[h,j]
template <int H>
__global__ void final_matvec(const unsigned int* __restrict__ pooled_u,
                             const float* __restrict__ Wd,
                             const float* __restrict__ bd,
                             float* __restrict__ out,
                             int HOUT) {
    int j = threadIdx.x;
    if (j >= HOUT) return;
    float acc = bd[j];
#pragma unroll
    for (int hh = 0; hh < H; ++hh) acc += k2f(pooled_u[hh]) * Wd[hh * HOUT + j];
    out[j] = acc;
}

extern "C" void kernel_launch(void* const* d_in, const int* in_sizes, int n_in,
                              void* d_out, int out_size, void* d_ws, size_t ws_size,
                              hipStream_t stream) {
    const float* x     = (const float*)d_in[0];
    const float* e     = (const float*)d_in[1];
    const int*   src   = (const int*)d_in[2];
    const int*   dst   = (const int*)d_in[3];
    const float* Wk    = (const float*)d_in[4];
    const float* bk    = (const float*)d_in[5];
    const float* Wr    = (const float*)d_in[6];
    const float* br    = (const float*)d_in[7];
    const float* gamma = (const float*)d_in[8];
    const float* beta  = (const float*)d_in[9];
    const float* mmean = (const float*)d_in[10];
    const float* mvar  = (const float*)d_in[11];
    const float* Wd    = (const float*)d_in[12];
    const float* bd    = (const float*)d_in[13];

    constexpr int S = 8, F = 16, H = 16;
    const int E = in_sizes[2];
    const int N = in_sizes[0] / F;
    const int HOUT = in_sizes[13];  // 3

    // workspace layout
    _Float16* y2h = (_Float16*)d_ws;                    // N*(S+1)*H fp16
    float* agg = (float*)(y2h + (size_t)N * (S + 1) * H);  // N*H fp32
    unsigned int* pooled_u = (unsigned int*)(agg + (size_t)N * H);  // H

    const int T = 256;
    int nh = N * H;
    node_pre<S, F, H><<<(nh + T - 1) / T, T, 0, stream>>>(
        x, Wk, bk, Wr, br, y2h, agg, pooled_u, N);

    long long et = (long long)E * 2;
    edge_scatter<S, H><<<(int)((et + T - 1) / T), T, 0, stream>>>(
        e, src, dst, y2h, agg, E);

    bn_relu_max<H><<<1024, T, 0, stream>>>(agg, gamma, beta, mmean, mvar, pooled_u, N);

    final_matvec<H><<<1, 64, 0, stream>>>(pooled_u, Wd, bd, (float*)d_out, HOUT);
}

// Round 5
// 141.094 us; speedup vs baseline: 1.7270x; 1.7270x over previous
//
#include <hip/hip_runtime.h>

#define BN_EPS 1e-3f

typedef float vf4 __attribute__((ext_vector_type(4)));      // native vector for builtins
typedef _Float16 half8 __attribute__((ext_vector_type(8))); // 16B of fp16

// ---- order-preserving float<->uint key for atomicMax on floats ----
__device__ __forceinline__ unsigned int f2k(float f) {
    unsigned int u = __float_as_uint(f);
    return (u & 0x80000000u) ? ~u : (u | 0x80000000u);
}
__device__ __forceinline__ float k2f(unsigned int u) {
    return __uint_as_float((u & 0x80000000u) ? (u & 0x7FFFFFFFu) : ~u);
}

// Kernel 1: per-node precompute.
//   y2h[n,s,h] = (fp16) sum_f x[n,f] * Wk[s, f*H + h]   for s<8
//   y2h[n,8,h] = (fp16) sum_f x[n,f] * bk[f*H + h]      (bias row, edge coeff 1.0)
//   agg[n,h]   = sum_f x[n,f] * Wr[f,h] + br[h]         (base folded into agg init)
// Also initializes pooled_u (block 0).
template <int S, int F, int H>
__global__ void node_pre(const float* __restrict__ x,
                         const float* __restrict__ Wk,
                         const float* __restrict__ bk,
                         const float* __restrict__ Wr,
                         const float* __restrict__ br,
                         _Float16* __restrict__ y2h,   // [N, S+1, H] fp16
                         float* __restrict__ agg,      // [N, H] fp32
                         unsigned int* __restrict__ pooled_u,
                         int N) {
    if (blockIdx.x == 0 && threadIdx.x < H) pooled_u[threadIdx.x] = 0u;

    int t = blockIdx.x * blockDim.x + threadIdx.x;
    int n = t / H;
    int h = t % H;
    if (n >= N) return;

    float xf[F];
#pragma unroll
    for (int f = 0; f < F; ++f) xf[f] = x[n * F + f];

    _Float16* yrow = y2h + (size_t)n * (S + 1) * H + h;
#pragma unroll
    for (int s = 0; s < S; ++s) {
        float acc = 0.f;
#pragma unroll
        for (int f = 0; f < F; ++f) acc += xf[f] * Wk[(s * F + f) * H + h];
        yrow[s * H] = (_Float16)acc;
    }

    float accb = 0.f, accr = 0.f;
#pragma unroll
    for (int f = 0; f < F; ++f) {
        accb += xf[f] * bk[f * H + h];
        accr += xf[f] * Wr[f * H + h];
    }
    yrow[S * H] = (_Float16)accb;             // bias row (coeff 1.0 per edge)
    agg[(size_t)n * H + h] = accr + br[h];    // base folded into agg init
}

// Kernel 2: per-edge message + scatter-add.
// Phase A (gather): 2 lanes/edge, 16B half8 gathers of y2h -> msg in LDS.
// Phase B (scatter): lanes remapped edge-major (4 edges x 16 ch per wave
// instruction) so all 16 channels of an edge coalesce into 2 x 32B sectors.
// 128 edges per block of 256 threads.
template <int S, int H>
__global__ void edge_scatter(const float* __restrict__ efeat,
                             const int* __restrict__ src,
                             const int* __restrict__ dst,
                             const _Float16* __restrict__ y2h,  // [N, S+1, H]
                             float* __restrict__ agg,
                             int E) {
    __shared__ float msg[H][128];   // h-major: bank = e_local%32 -> 2-way max (free)
    __shared__ int sdst[128];

    int t = threadIdx.x;
    int e0 = blockIdx.x * 128;

    // ---- Phase A: gather + per-edge dense mini-GEMV ----
    int el = t >> 1;
    int hi = t & 1;          // which 8-wide half of the H=16 row
    int edge = e0 + el;

    float m[8] = {0.f, 0.f, 0.f, 0.f, 0.f, 0.f, 0.f, 0.f};
    if (edge < E) {
        if (hi == 0) sdst[el] = __builtin_nontemporal_load(dst + edge);
        int sn = __builtin_nontemporal_load(src + edge);

        const vf4* e4 = (const vf4*)(efeat + (size_t)edge * S);
        vf4 ea = __builtin_nontemporal_load(e4);
        vf4 eb = __builtin_nontemporal_load(e4 + 1);
        float es[S + 1] = {ea.x, ea.y, ea.z, ea.w, eb.x, eb.y, eb.z, eb.w, 1.0f};

        const _Float16* yb = y2h + (size_t)sn * (S + 1) * H + hi * 8;
#pragma unroll
        for (int s = 0; s <= S; ++s) {
            half8 hv = *(const half8*)(yb + s * H);
#pragma unroll
            for (int j = 0; j < 8; ++j) m[j] += es[s] * (float)hv[j];
        }
    }
#pragma unroll
    for (int j = 0; j < 8; ++j) msg[hi * 8 + j][el] = m[j];

    __syncthreads();

    // ---- Phase B: edge-major coalesced atomics ----
    int e2 = t >> 4;         // 0..15
    int h = t & 15;
#pragma unroll
    for (int p = 0; p < 8; ++p) {
        int el2 = p * 16 + e2;
        if (e0 + el2 < E) {
            unsafeAtomicAdd(&agg[(size_t)sdst[el2] * H + h], msg[h][el2]);
        }
    }
}

// Kernel 3: h = BN(relu(agg)); global max per h.
template <int H>
__global__ void bn_relu_max(const float* __restrict__ agg,
                            const float* __restrict__ gamma,
                            const float* __restrict__ beta,
                            const float* __restrict__ mmean,
                            const float* __restrict__ mvar,
                            unsigned int* __restrict__ pooled_u,
                            int N) {
    __shared__ unsigned int smax[H];
    if (threadIdx.x < H) smax[threadIdx.x] = 0u;
    __syncthreads();

    int t = blockIdx.x * blockDim.x + threadIdx.x;
    int stride = gridDim.x * blockDim.x;  // multiple of H
    int h = t % H;

    float scale = gamma[h] * rsqrtf(mvar[h] + BN_EPS);
    float shift = beta[h] - mmean[h] * scale;

    float best = -INFINITY;
    int total = N * H;
    for (int i = t; i < total; i += stride) {
        float v = agg[i];
        v = v > 0.f ? v : 0.f;          // relu
        v = v * scale + shift;          // BN (inference)
        best = fmaxf(best, v);
    }
    atomicMax(&smax[h], f2k(best));
    __syncthreads();
    if (threadIdx.x < H) atomicMax(&pooled_u[threadIdx.x], smax[threadIdx.x]);
}

// Kernel 4: out[j] = bd[j] + sum_h pooled[h] * Wd[h,j]
template <int H>
__global__ void final_matvec(const unsigned int* __restrict__ pooled_u,
                             const float* __restrict__ Wd,
                             const float* __restrict__ bd,
                             float* __restrict__ out,
                             int HOUT) {
    int j = threadIdx.x;
    if (j >= HOUT) return;
    float acc = bd[j];
#pragma unroll
    for (int hh = 0; hh < H; ++hh) acc += k2f(pooled_u[hh]) * Wd[hh * HOUT + j];
    out[j] = acc;
}

extern "C" void kernel_launch(void* const* d_in, const int* in_sizes, int n_in,
                              void* d_out, int out_size, void* d_ws, size_t ws_size,
                              hipStream_t stream) {
    const float* x     = (const float*)d_in[0];
    const float* e     = (const float*)d_in[1];
    const int*   src   = (const int*)d_in[2];
    const int*   dst   = (const int*)d_in[3];
    const float* Wk    = (const float*)d_in[4];
    const float* bk    = (const float*)d_in[5];
    const float* Wr    = (const float*)d_in[6];
    const float* br    = (const float*)d_in[7];
    const float* gamma = (const float*)d_in[8];
    const float* beta  = (const float*)d_in[9];
    const float* mmean = (const float*)d_in[10];
    const float* mvar  = (const float*)d_in[11];
    const float* Wd    = (const float*)d_in[12];
    const float* bd    = (const float*)d_in[13];

    constexpr int S = 8, F = 16, H = 16;
    const int E = in_sizes[2];
    const int N = in_sizes[0] / F;
    const int HOUT = in_sizes[13];  // 3

    // workspace layout
    _Float16* y2h = (_Float16*)d_ws;                       // N*(S+1)*H fp16
    float* agg = (float*)(y2h + (size_t)N * (S + 1) * H);  // N*H fp32
    unsigned int* pooled_u = (unsigned int*)(agg + (size_t)N * H);  // H

    const int T = 256;
    int nh = N * H;
    node_pre<S, F, H><<<(nh + T - 1) / T, T, 0, stream>>>(
        x, Wk, bk, Wr, br, y2h, agg, pooled_u, N);

    int eblocks = (E + 127) / 128;
    edge_scatter<S, H><<<eblocks, T, 0, stream>>>(
        e, src, dst, y2h, agg, E);

    bn_relu_max<H><<<1024, T, 0, stream>>>(agg, gamma, beta, mmean, mvar, pooled_u, N);

    final_matvec<H><<<1, 64, 0, stream>>>(pooled_u, Wd, bd, (float*)d_out, HOUT);
}